// Round 1
// baseline (40.596 us; speedup 1.0000x reference)
//
#include <hip/hip_runtime.h>

// Problem constants (from reference)
#define NUM_CLUSTER 8
#define PER 16
#define BATCH 4
#define SEQ_L 96
#define D_MODEL 512
#define NI (NUM_CLUSTER * PER)        // 128 tokens
#define CHUNK (SEQ_L * D_MODEL)       // 49152 floats per (b,i) chunk
#define CHUNK_V4 (CHUNK / 4)          // 12288 float4 per chunk

// Kernel 1: compute per-i source chunk base = y_pred[i]*BATCH*PER + rank[i]
// rank[i] = number of j < i with y_pred[j] == y_pred[i]
__global__ void compute_src_base(const int* __restrict__ y_pred,
                                 int* __restrict__ src_base) {
    int i = threadIdx.x;              // 0..127, single block of 128
    int c = y_pred[i];
    int rank = 0;
    for (int j = 0; j < i; ++j)
        rank += (y_pred[j] == c);
    // input layout (cluster, batch, per, L, D): chunk index = (c*BATCH + b)*PER + rank
    src_base[i] = c * (BATCH * PER) + rank;   // add b*PER in the copy kernel
}

// Kernel 2: chunk-permuted vectorized copy.
// out[(b*NI + i)] chunk <- in[src_base[i] + b*PER] chunk
__global__ void gather_copy(const float4* __restrict__ x,
                            const int* __restrict__ src_base,
                            float4* __restrict__ out) {
    int bi = blockIdx.y;              // 0..511 : b*NI + i
    int b  = bi >> 7;                 // / 128
    int i  = bi & (NI - 1);           // % 128
    int sc = src_base[i] + b * PER;   // source chunk index

    const float4* __restrict__ src = x   + (size_t)sc * CHUNK_V4;
    float4* __restrict__       dst = out + (size_t)bi * CHUNK_V4;

    int stride = gridDim.x * blockDim.x;                 // 12*256 = 3072
    for (int k = blockIdx.x * blockDim.x + threadIdx.x;  // 4 iters/thread
         k < CHUNK_V4; k += stride)
        dst[k] = src[k];
}

extern "C" void kernel_launch(void* const* d_in, const int* in_sizes, int n_in,
                              void* d_out, int out_size, void* d_ws, size_t ws_size,
                              hipStream_t stream) {
    const float* x_enc_hf = (const float*)d_in[0];   // (8,4,16,96,512) fp32
    const int*   y_pred   = (const int*)d_in[1];     // (128,) int32
    // d_in[2] is the Python scalar B (==4), baked in as BATCH.
    float* out = (float*)d_out;                      // (4,128,96,512) fp32
    int* src_base = (int*)d_ws;                      // 128 ints

    compute_src_base<<<1, NI, 0, stream>>>(y_pred, src_base);
    gather_copy<<<dim3(12, BATCH * NI), 256, 0, stream>>>(
        (const float4*)x_enc_hf, src_base, (float4*)out);
}

// Round 2
// 35.027 us; speedup vs baseline: 1.1590x; 1.1590x over previous
//
#include <hip/hip_runtime.h>

// Problem constants (from reference)
#define NUM_CLUSTER 8
#define PER 16
#define BATCH 4
#define SEQ_L 96
#define D_MODEL 512
#define NI (NUM_CLUSTER * PER)        // 128 tokens
#define CHUNK (SEQ_L * D_MODEL)       // 49152 floats per (b,i) chunk
#define CHUNK_V4 (CHUNK / 4)          // 12288 float4 per chunk

// Fused kernel: each block computes rank[i] in-place via ballot (2 waves over
// the 128-entry y_pred), then does a coalesced float4 chunk copy.
// out[(b*NI + i)] chunk <- in[(y_pred[i]*BATCH + b)*PER + rank[i]] chunk
__global__ void gather_copy(const float4* __restrict__ x,
                            const int* __restrict__ y_pred,
                            float4* __restrict__ out) {
    __shared__ int s_cnt[2];

    int bi = blockIdx.y;              // 0..511 : b*NI + i
    int b  = bi >> 7;                 // / 128
    int i  = bi & (NI - 1);           // % 128

    int c = y_pred[i];                // broadcast load, L2-resident
    int t = threadIdx.x;
    if (t < NI) {                     // waves 0 and 1 only
        bool pred = (t < i) && (y_pred[t] == c);
        unsigned long long m = __ballot(pred);
        if ((t & 63) == 0) s_cnt[t >> 6] = __popcll(m);
    }
    __syncthreads();
    int rank = s_cnt[0] + s_cnt[1];   // = #{j < i : y_pred[j] == c}

    // input layout (cluster, batch, per, L, D)
    int sc = c * (BATCH * PER) + b * PER + rank;

    const float4* __restrict__ src = x   + (size_t)sc * CHUNK_V4;
    float4* __restrict__       dst = out + (size_t)bi * CHUNK_V4;

    int stride = gridDim.x * blockDim.x;                 // 12*256 = 3072
    for (int k = blockIdx.x * blockDim.x + t;            // 4 iters/thread
         k < CHUNK_V4; k += stride)
        dst[k] = src[k];
}

extern "C" void kernel_launch(void* const* d_in, const int* in_sizes, int n_in,
                              void* d_out, int out_size, void* d_ws, size_t ws_size,
                              hipStream_t stream) {
    const float* x_enc_hf = (const float*)d_in[0];   // (8,4,16,96,512) fp32
    const int*   y_pred   = (const int*)d_in[1];     // (128,) int32
    // d_in[2] is the Python scalar B (==4), baked in as BATCH.
    float* out = (float*)d_out;                      // (4,128,96,512) fp32

    gather_copy<<<dim3(12, BATCH * NI), 256, 0, stream>>>(
        (const float4*)x_enc_hf, y_pred, (float4*)out);
}